// Round 1
// baseline (50.999 us; speedup 1.0000x reference)
//
#include <hip/hip_runtime.h>
#include <hip/hip_bf16.h>
#include <math.h>

// SPP max-pool pyramid: x [B=32, H=64, W=64, C=512] f32 (NHWC, C innermost)
// scales (1,1),(2,2),(4,4),(8,8). Output row layout per batch (43520 floats):
//   [0,512)        : 1x1 scale
//   [512,2560)     : 2x2 scale, (i2*2+j2)*512 + c
//   [2560,10752)   : 4x4 scale, (i4*4+j4)*512 + c
//   [10752,43520)  : 8x8 scale, (i8*8+j8)*512 + c
// All bin sizes divide evenly (64/ph exact), so uniform bins.

#define C_F4 128          // 512 channels / 4 = 128 float4 per spatial position
#define ROW_OUT 43520     // 85 * 512
#define S8_OFF 10752
#define S4_OFF 2560
#define S2_OFF 512

static __device__ __forceinline__ float4 f4max(float4 a, float4 b) {
    float4 r;
    r.x = fmaxf(a.x, b.x);
    r.y = fmaxf(a.y, b.y);
    r.z = fmaxf(a.z, b.z);
    r.w = fmaxf(a.w, b.w);
    return r;
}

// Kernel 1: one block per (b, i8, j8). 128 threads, each owns one float4
// channel slice; max over the 8x8 spatial patch (64 coalesced float4 loads).
__global__ __launch_bounds__(128) void spp_pool8(const float* __restrict__ x,
                                                 float* __restrict__ out) {
    const int blk = blockIdx.x;           // 0..2047
    const int b  = blk >> 6;
    const int rem = blk & 63;
    const int i8 = rem >> 3;
    const int j8 = rem & 7;
    const int tid = threadIdx.x;          // 0..127

    // top-left corner of this 8x8 patch, in float4 units
    const float4* src = reinterpret_cast<const float4*>(x)
                      + (size_t)(((b * 64 + i8 * 8) * 64) + j8 * 8) * C_F4 + tid;
    // strides in float4 units: next w = 128, next h = 64*128 = 8192

    float4 m = src[0];
    #pragma unroll 2
    for (int h = 0; h < 8; ++h) {
        #pragma unroll
        for (int w = 0; w < 8; ++w) {
            if (h == 0 && w == 0) continue;
            m = f4max(m, src[h * 8192 + w * 128]);
        }
    }

    float4* dst = reinterpret_cast<float4*>(out + (size_t)b * ROW_OUT + S8_OFF
                                            + (i8 * 8 + j8) * 512);
    dst[tid] = m;
}

// Kernel 2: derive 4x4 / 2x2 / 1x1 scales from the 8x8 scale already in out.
// 4096 threads total: thread = (b, c4).
__global__ __launch_bounds__(256) void spp_pyramid(float* __restrict__ out) {
    const int t = blockIdx.x * blockDim.x + threadIdx.x;  // 0..4095
    const int b  = t >> 7;
    const int c4 = t & 127;

    float* row = out + (size_t)b * ROW_OUT;
    const float4* p8 = reinterpret_cast<const float4*>(row + S8_OFF) + c4;
    // p8[bin * 128] where bin = i8*8 + j8

    const float4 ninf = make_float4(-INFINITY, -INFINITY, -INFINITY, -INFINITY);
    float4 v1 = ninf;
    float4 v2_00 = ninf, v2_01 = ninf, v2_10 = ninf, v2_11 = ninf;

    #pragma unroll
    for (int i4 = 0; i4 < 4; ++i4) {
        #pragma unroll
        for (int j4 = 0; j4 < 4; ++j4) {
            float4 m = ninf;
            #pragma unroll
            for (int di = 0; di < 2; ++di) {
                #pragma unroll
                for (int dj = 0; dj < 2; ++dj) {
                    const int bin = (2 * i4 + di) * 8 + (2 * j4 + dj);
                    m = f4max(m, p8[bin * C_F4]);
                }
            }
            reinterpret_cast<float4*>(row + S4_OFF + (i4 * 4 + j4) * 512)[c4] = m;
            // fold into 2x2 accumulators (compile-time selection: loops unrolled)
            if (i4 < 2) {
                if (j4 < 2) v2_00 = f4max(v2_00, m); else v2_01 = f4max(v2_01, m);
            } else {
                if (j4 < 2) v2_10 = f4max(v2_10, m); else v2_11 = f4max(v2_11, m);
            }
        }
    }

    reinterpret_cast<float4*>(row + S2_OFF + 0 * 512)[c4] = v2_00;
    reinterpret_cast<float4*>(row + S2_OFF + 1 * 512)[c4] = v2_01;
    reinterpret_cast<float4*>(row + S2_OFF + 2 * 512)[c4] = v2_10;
    reinterpret_cast<float4*>(row + S2_OFF + 3 * 512)[c4] = v2_11;

    v1 = f4max(f4max(v2_00, v2_01), f4max(v2_10, v2_11));
    reinterpret_cast<float4*>(row)[c4] = v1;
}

extern "C" void kernel_launch(void* const* d_in, const int* in_sizes, int n_in,
                              void* d_out, int out_size, void* d_ws, size_t ws_size,
                              hipStream_t stream) {
    const float* x = (const float*)d_in[0];
    float* out = (float*)d_out;

    // Kernel 1: 32 batches * 64 bins = 2048 blocks
    spp_pool8<<<2048, 128, 0, stream>>>(x, out);
    // Kernel 2: 32 batches * 128 c4-slices = 4096 threads
    spp_pyramid<<<16, 256, 0, stream>>>(out);
}

// Round 2
// 47.814 us; speedup vs baseline: 1.0666x; 1.0666x over previous
//
#include <hip/hip_runtime.h>
#include <hip/hip_bf16.h>
#include <math.h>

// SPP max-pool pyramid: x [B=32, H=64, W=64, C=512] f32 (NHWC, C innermost)
// scales (1,1),(2,2),(4,4),(8,8). Output row layout per batch (43520 floats):
//   [0,512)        : 1x1 scale
//   [512,2560)     : 2x2 scale, (i2*2+j2)*512 + c
//   [2560,10752)   : 4x4 scale, (i4*4+j4)*512 + c
//   [10752,43520)  : 8x8 scale, (i8*8+j8)*512 + c
// All bin sizes divide 64 evenly, so uniform bins (last-bin-extends is a no-op).

#define C_F4 128          // 512 channels / 4 = 128 float4 per spatial position
#define ROW_OUT 43520     // 85 * 512
#define S8_OFF 10752
#define S4_OFF 2560
#define S2_OFF 512

static __device__ __forceinline__ float4 f4max(float4 a, float4 b) {
    float4 r;
    r.x = fmaxf(a.x, b.x);
    r.y = fmaxf(a.y, b.y);
    r.z = fmaxf(a.z, b.z);
    r.w = fmaxf(a.w, b.w);
    return r;
}

// Kernel 1: one block per (b, i8, j8). 128 threads, each owns one float4
// channel slice; max over the 8x8 spatial patch (64 coalesced float4 loads).
// unroll 4: 32 loads in flight per thread for memory-level parallelism.
__global__ __launch_bounds__(128) void spp_pool8(const float* __restrict__ x,
                                                 float* __restrict__ out) {
    const int blk = blockIdx.x;           // 0..2047
    const int b  = blk >> 6;
    const int rem = blk & 63;
    const int i8 = rem >> 3;
    const int j8 = rem & 7;
    const int tid = threadIdx.x;          // 0..127

    // top-left corner of this 8x8 patch, in float4 units
    const float4* src = reinterpret_cast<const float4*>(x)
                      + (size_t)(((b * 64 + i8 * 8) * 64) + j8 * 8) * C_F4 + tid;
    // strides in float4 units: next w = 128, next h = 64*128 = 8192

    float4 m = src[0];
    #pragma unroll 4
    for (int h = 0; h < 8; ++h) {
        #pragma unroll
        for (int w = 0; w < 8; ++w) {
            if (h == 0 && w == 0) continue;
            m = f4max(m, src[h * 8192 + w * 128]);
        }
    }

    float4* dst = reinterpret_cast<float4*>(out + (size_t)b * ROW_OUT + S8_OFF
                                            + (i8 * 8 + j8) * 512);
    dst[tid] = m;
}

// Kernel 2: derive 4x4 / 2x2 / 1x1 from the 8x8 scale already in out.
// One block per batch, 512 threads = (quadrant q, c4). Each thread reads the
// 16 8x8-bins of its 2x2-quadrant (16 independent float4 loads), writes its
// four 4x4 bins and one 2x2 bin; 1x1 is combined across quadrants via LDS.
__global__ __launch_bounds__(512) void spp_pyramid(float* __restrict__ out) {
    const int b   = blockIdx.x;           // 0..31
    const int tid = threadIdx.x;          // 0..511
    const int q   = tid >> 7;             // quadrant 0..3
    const int c4  = tid & 127;
    const int i2  = q >> 1;
    const int j2  = q & 1;

    float* row = out + (size_t)b * ROW_OUT;
    const float4* p8 = reinterpret_cast<const float4*>(row + S8_OFF) + c4;
    // p8[bin * 128] where bin = i8*8 + j8

    const float4 ninf = make_float4(-INFINITY, -INFINITY, -INFINITY, -INFINITY);
    float4 v2 = ninf;

    #pragma unroll
    for (int di4 = 0; di4 < 2; ++di4) {
        #pragma unroll
        for (int dj4 = 0; dj4 < 2; ++dj4) {
            const int i4 = i2 * 2 + di4;
            const int j4 = j2 * 2 + dj4;
            float4 m = ninf;
            #pragma unroll
            for (int di = 0; di < 2; ++di) {
                #pragma unroll
                for (int dj = 0; dj < 2; ++dj) {
                    const int bin = (2 * i4 + di) * 8 + (2 * j4 + dj);
                    m = f4max(m, p8[bin * C_F4]);
                }
            }
            reinterpret_cast<float4*>(row + S4_OFF + (i4 * 4 + j4) * 512)[c4] = m;
            v2 = f4max(v2, m);
        }
    }

    reinterpret_cast<float4*>(row + S2_OFF + (i2 * 2 + j2) * 512)[c4] = v2;

    __shared__ float4 ls[4][128];
    ls[q][c4] = v2;
    __syncthreads();
    if (q == 0) {
        float4 v1 = f4max(f4max(ls[0][c4], ls[1][c4]),
                          f4max(ls[2][c4], ls[3][c4]));
        reinterpret_cast<float4*>(row)[c4] = v1;
    }
}

extern "C" void kernel_launch(void* const* d_in, const int* in_sizes, int n_in,
                              void* d_out, int out_size, void* d_ws, size_t ws_size,
                              hipStream_t stream) {
    const float* x = (const float*)d_in[0];
    float* out = (float*)d_out;

    // Kernel 1: 32 batches * 64 bins = 2048 blocks
    spp_pool8<<<2048, 128, 0, stream>>>(x, out);
    // Kernel 2: one block per batch
    spp_pyramid<<<32, 512, 0, stream>>>(out);
}

// Round 3
// 47.415 us; speedup vs baseline: 1.0756x; 1.0084x over previous
//
#include <hip/hip_runtime.h>
#include <hip/hip_bf16.h>
#include <math.h>

// SPP max-pool pyramid: x [B=32, H=64, W=64, C=512] f32 (NHWC, C innermost)
// scales (1,1),(2,2),(4,4),(8,8). Output row layout per batch (43520 floats):
//   [0,512)        : 1x1 scale
//   [512,2560)     : 2x2 scale, (i2*2+j2)*512 + c
//   [2560,10752)   : 4x4 scale, (i4*4+j4)*512 + c
//   [10752,43520)  : 8x8 scale, (i8*8+j8)*512 + c
// All bin sizes divide 64 evenly, so uniform bins (last-bin-extends is a no-op).

#define C_F4 128          // 512 channels / 4 = 128 float4 per spatial position
#define ROW_OUT 43520     // 85 * 512
#define S8_OFF 10752
#define S4_OFF 2560
#define S2_OFF 512

static __device__ __forceinline__ float4 f4max(float4 a, float4 b) {
    float4 r;
    r.x = fmaxf(a.x, b.x);
    r.y = fmaxf(a.y, b.y);
    r.z = fmaxf(a.z, b.z);
    r.w = fmaxf(a.w, b.w);
    return r;
}

// Kernel 1: one block per (b, i4, j4) = 512 blocks x 256 threads.
// Thread = (s, c4): s in {0,1} picks the top/bottom 8-row band of the 16x16
// patch; each band holds two 8x8 bins. Each thread maxes 128 coalesced float4
// loads (2 bins x 64), writes both s8 bins, then the block's s4 bin is the
// LDS-combined max of the two bands.
__global__ __launch_bounds__(256) void spp_pool84(const float* __restrict__ x,
                                                  float* __restrict__ out) {
    const int blk = blockIdx.x;           // 0..511
    const int b   = blk >> 4;
    const int rem = blk & 15;
    const int i4  = rem >> 2;
    const int j4  = rem & 3;
    const int tid = threadIdx.x;          // 0..255
    const int s   = tid >> 7;             // band 0/1
    const int c4  = tid & 127;

    const int row0 = i4 * 16 + s * 8;
    const float4* src = reinterpret_cast<const float4*>(x)
                      + (size_t)((b * 64 + row0) * 64 + j4 * 16) * C_F4 + c4;
    // float4 strides: next col = 128, next row = 64*128 = 8192

    float4 m0 = src[0];
    float4 m1 = src[8 * 128];
    #pragma unroll 2
    for (int h = 0; h < 8; ++h) {
        #pragma unroll
        for (int w = 0; w < 8; ++w) {
            if (h == 0 && w == 0) continue;
            m0 = f4max(m0, src[h * 8192 + w * 128]);
            m1 = f4max(m1, src[h * 8192 + (w + 8) * 128]);
        }
    }

    float* row = out + (size_t)b * ROW_OUT;
    const int i8 = 2 * i4 + s;
    const int j8 = 2 * j4;
    reinterpret_cast<float4*>(row + S8_OFF + (i8 * 8 + j8) * 512)[c4]     = m0;
    reinterpret_cast<float4*>(row + S8_OFF + (i8 * 8 + j8 + 1) * 512)[c4] = m1;

    __shared__ float4 ls[2][128];
    ls[s][c4] = f4max(m0, m1);
    __syncthreads();
    if (s == 0) {
        float4 v4 = f4max(ls[0][c4], ls[1][c4]);
        reinterpret_cast<float4*>(row + S4_OFF + (i4 * 4 + j4) * 512)[c4] = v4;
    }
}

// Kernel 2: derive 2x2 / 1x1 from the 4x4 scale (L2-hot, 1 MB read).
// One block per batch, 512 threads = (quadrant q, c4); 4 loads per thread.
__global__ __launch_bounds__(512) void spp_tail(float* __restrict__ out) {
    const int b   = blockIdx.x;           // 0..31
    const int tid = threadIdx.x;          // 0..511
    const int q   = tid >> 7;             // quadrant 0..3
    const int c4  = tid & 127;
    const int i2  = q >> 1;
    const int j2  = q & 1;

    float* row = out + (size_t)b * ROW_OUT;
    const float4* p4 = reinterpret_cast<const float4*>(row + S4_OFF) + c4;

    float4 m = p4[((2 * i2) * 4 + 2 * j2) * C_F4];
    m = f4max(m, p4[((2 * i2) * 4 + 2 * j2 + 1) * C_F4]);
    m = f4max(m, p4[((2 * i2 + 1) * 4 + 2 * j2) * C_F4]);
    m = f4max(m, p4[((2 * i2 + 1) * 4 + 2 * j2 + 1) * C_F4]);

    reinterpret_cast<float4*>(row + S2_OFF + q * 512)[c4] = m;

    __shared__ float4 ls[4][128];
    ls[q][c4] = m;
    __syncthreads();
    if (q == 0) {
        float4 v1 = f4max(f4max(ls[0][c4], ls[1][c4]),
                          f4max(ls[2][c4], ls[3][c4]));
        reinterpret_cast<float4*>(row)[c4] = v1;
    }
}

extern "C" void kernel_launch(void* const* d_in, const int* in_sizes, int n_in,
                              void* d_out, int out_size, void* d_ws, size_t ws_size,
                              hipStream_t stream) {
    const float* x = (const float*)d_in[0];
    float* out = (float*)d_out;

    // Kernel 1: 32 batches * 16 (i4,j4) tiles = 512 blocks
    spp_pool84<<<512, 256, 0, stream>>>(x, out);
    // Kernel 2: one block per batch
    spp_tail<<<32, 512, 0, stream>>>(out);
}